// Round 18
// baseline (187.174 us; speedup 1.0000x reference)
//
#include <hip/hip_runtime.h>
#include <hip/hip_bf16.h>
#include <cstdint>

#define NPIX 16384   // h*w = 128*128
#define BATCH 8
#define CDIM 256

typedef __bf16 bh8 __attribute__((ext_vector_type(8)));
typedef __bf16 bh4 __attribute__((ext_vector_type(4)));
typedef float  fx4 __attribute__((ext_vector_type(4)));

__device__ __forceinline__ void gload16(const void* g, void* l) {
  __builtin_amdgcn_global_load_lds(
      (const __attribute__((address_space(1))) uint32_t*)g,
      (__attribute__((address_space(3))) uint32_t*)l, 16, 0, 0);
}

__device__ __forceinline__ fx4 mfma16(bh8 a, bh8 b, fx4 c) {
  return __builtin_amdgcn_mfma_f32_16x16x32_bf16(a, b, c, 0, 0, 0);
}

__device__ __forceinline__ void pbar() {
  asm volatile("" ::: "memory");
  __builtin_amdgcn_s_barrier();
  asm volatile("" ::: "memory");
}

// -------- pass 0: weight prep (wqb bf16 k/v rows + WqT) ---------------------
__global__ __launch_bounds__(256) void prep_w(const float* __restrict__ w_qkv,
                                              __bf16* __restrict__ wqb,
                                              __bf16* __restrict__ wqT) {
  __shared__ float tile[32][33];
  int bid = blockIdx.x;
  if (bid < 512) {
    int i = bid * 256 + threadIdx.x;
    wqb[i] = (__bf16)w_qkv[256 * 256 + i];
  } else {
    bid -= 512;
    const int t0 = (bid & 7) * 32, o0 = (bid >> 3) * 32;
    const int tx = threadIdx.x & 31, ty = threadIdx.x >> 5;
#pragma unroll
    for (int j = 0; j < 4; ++j) {
      int r = ty * 4 + j;
      tile[r][tx] = w_qkv[(size_t)(o0 + r) * 256 + t0 + tx];
    }
    __syncthreads();
#pragma unroll
    for (int j = 0; j < 4; ++j) {
      int tl = ty * 4 + j;
      wqT[(size_t)(t0 + tl) * 256 + o0 + tx] = (__bf16)tile[tx][tl];
    }
  }
}

// ====== 128x128 tile GEMM, K=256 as 4 x BK=64, FUSED x-transpose staging ====
// 256 threads / 4 waves (2x2). A: gload16 (weights). B: reg-staged directly
// from f32 x [c][px] -> cvt bf16 -> ds_write_b64 into swizzled [px][c] LDS
// (chunk ^ (px&7)) -- identical layout COMP always read; xT is GONE.
// Pre-COMP sync = __syncthreads() (drains vmcnt+lgkmcnt; no manual counts).
// EPI==0: by=head-pair hp; A rows = 64 k || 64 v; epilogue S+Z (unchanged).
// EPI==1: by=row-half of W3[b]; f32 out + bias via LDS bounce (unchanged).

#define STA(kt)                                                                \
  do {                                                                         \
    _Pragma("unroll") for (int i_ = 0; i_ < 4; ++i_) {                         \
      int j_ = i_ * 256 + tid;                                                 \
      int row_ = j_ >> 3, c_ = j_ & 7;                                         \
      int sc_ = c_ ^ (row_ & 7);                                               \
      const __bf16* sb_;                                                       \
      if (EPI == 0) sb_ = (i_ < 2) ? Abk + (size_t)row_ * 256                  \
                                   : Abv + (size_t)(row_ - 64) * 256;          \
      else          sb_ = Ab + (size_t)row_ * 256;                             \
      gload16(sb_ + (kt)*64 + sc_ * 8, (__bf16*)smem + j_ * 8);                \
    }                                                                          \
  } while (0)

// fused-transpose B staging: half rr2 covers c-range [rr2*32, rr2*32+32)
// thread: cq = tid&7 (c-quad), pxb = tid>>3 (4 px). 4 fx4 reads (contiguous
// 128B per 8-lane group), 4 b64 swizzled LDS writes.
#define BSTG(kt, rr2)                                                          \
  do {                                                                         \
    const float* xr_ = Xb + (size_t)((kt)*64 + (rr2)*32 + cq * 4) * NPIX +     \
                       pxb * 4;                                                \
    fx4 r0_ = *(const fx4*)(xr_);                                              \
    fx4 r1_ = *(const fx4*)(xr_ + NPIX);                                       \
    fx4 r2_ = *(const fx4*)(xr_ + 2 * NPIX);                                   \
    fx4 r3_ = *(const fx4*)(xr_ + 3 * NPIX);                                   \
    const int chunk_ = (rr2)*4 + (cq >> 1);                                    \
    _Pragma("unroll") for (int j_ = 0; j_ < 4; ++j_) {                         \
      int px_ = pxb * 4 + j_;                                                  \
      int byo_ = px_ * 128 + ((chunk_ ^ (px_ & 7)) << 4) + (cq & 1) * 8;       \
      bh4 pk_;                                                                 \
      pk_[0] = (__bf16)r0_[j_]; pk_[1] = (__bf16)r1_[j_];                      \
      pk_[2] = (__bf16)r2_[j_]; pk_[3] = (__bf16)r3_[j_];                      \
      *(bh4*)(smem + 16384 + byo_) = pk_;                                      \
    }                                                                          \
  } while (0)

#define BSP ((__bf16*)(smem + 16384))

#define COMP()                                                                 \
  do {                                                                         \
    _Pragma("unroll") for (int ks_ = 0; ks_ < 2; ++ks_) {                      \
      bh8 a_[4], b_[4];                                                        \
      const int swk_ = (ks_ * 4 + fq) ^ (fr & 7);                              \
      _Pragma("unroll") for (int m_ = 0; m_ < 4; ++m_)                         \
        a_[m_] = *(const bh8*)&((__bf16*)smem)[(wm * 64 + m_ * 16 + fr) * 64 + \
                                               swk_ * 8];                      \
      _Pragma("unroll") for (int n_ = 0; n_ < 4; ++n_)                         \
        b_[n_] = *(const bh8*)&BSP[(wn * 64 + n_ * 16 + fr) * 64 + swk_ * 8];  \
      _Pragma("unroll") for (int m_ = 0; m_ < 4; ++m_)                         \
      _Pragma("unroll") for (int n_ = 0; n_ < 4; ++n_)                         \
        acc[m_][n_] = mfma16(a_[m_], b_[n_], acc[m_][n_]);                     \
    }                                                                          \
  } while (0)

template <int EPI>
__global__ __launch_bounds__(256, 3) void gemm256(
    const __bf16* __restrict__ A, const float* __restrict__ X,
    float* __restrict__ S_part, float* __restrict__ Zpart,
    const float* __restrict__ bias, float* __restrict__ fout) {
  __shared__ __align__(16) char smem[33024];
  const int tid = threadIdx.x;
  const int by = blockIdx.x;   // EPI0: head-pair hp; EPI1: row-half
  const int bx = blockIdx.y;   // pixel tile (adjacent by share it -> L2)
  const int b = blockIdx.z;
  const int lane = tid & 63, wid = tid >> 6;
  const int wm = wid >> 1, wn = wid & 1;
  const int fr = lane & 15, fq = lane >> 4;
  const int cq = tid & 7, pxb = tid >> 3;  // B-staging assignment
  const int hp = by;
  const __bf16* Abk = A + (size_t)(hp * 64) * 256;
  const __bf16* Abv = A + (size_t)(256 + hp * 64) * 256;
  const __bf16* Ab  = A + (size_t)b * 65536 + (size_t)by * 128 * 256;
  const float* Xb = X + (size_t)b * CDIM * NPIX + (size_t)bx * 128;

  fx4 acc[4][4] = {};

  STA(0); BSTG(0, 0); BSTG(0, 1); __syncthreads(); COMP(); pbar();
  STA(1); BSTG(1, 0); BSTG(1, 1); __syncthreads(); COMP(); pbar();
  STA(2); BSTG(2, 0); BSTG(2, 1); __syncthreads(); COMP(); pbar();
  STA(3); BSTG(3, 0); BSTG(3, 1); __syncthreads(); COMP(); pbar();

  if (EPI == 0) {
    // ---- epilogue A: Lk (exp(k), 64x128) @0, Lv (v, 64x128) @16384,
    // chunk-XOR swizzled 256B rows; zrow (64 f32) @32768.
    float* zrow = (float*)(smem + 32768);
    if (tid < 64) zrow[tid] = 0.f;
#pragma unroll
    for (int m = 0; m < 4; ++m)
#pragma unroll
      for (int n = 0; n < 4; ++n)
#pragma unroll
        for (int j = 0; j < 4; ++j) {
          int r = m * 16 + fq * 4 + j;             // 0..63 within k or v half
          int px = wn * 64 + n * 16 + fr;          // 0..127
          int pc = px >> 3;
          int byo = r * 256 + ((pc ^ (r & 7)) << 4) + (px & 7) * 2;
          if (wm == 0)
            *(__bf16*)(smem + byo) = (__bf16)__expf(acc[m][n][j]);
          else
            *(__bf16*)(smem + 16384 + byo) = (__bf16)acc[m][n][j];
        }
    pbar();
    {  // Z: 4 threads per k-row, 32 px each
      int r = tid >> 2, c0 = (tid & 3) * 32;
      float za = 0.f;
#pragma unroll
      for (int i2 = 0; i2 < 4; ++i2) {
        int pc = (c0 + i2 * 8) >> 3;
        bh8 ev = *(const bh8*)(smem + r * 256 + ((pc ^ (r & 7)) << 4));
#pragma unroll
        for (int jj = 0; jj < 8; ++jj) za += (float)ev[jj];
      }
      atomicAdd(&zrow[r], za);
    }
    // S: 8 tasks (2 heads x 4 quadrants) over 4 waves, 2 tasks/wave
    fx4 sac0 = {}, sac1 = {};
#pragma unroll
    for (int t2 = 0; t2 < 2; ++t2) {
      int tk = wid * 2 + t2;
      int hl = tk >> 2, quad = tk & 3;
      int drow = (quad >> 1) * 16, erow = (quad & 1) * 16;
      fx4 sac = {};
#pragma unroll
      for (int kt2 = 0; kt2 < 4; ++kt2) {
        int ra = hl * 32 + drow + fr;
        int rb = hl * 32 + erow + fr;
        int pc = kt2 * 4 + fq;
        bh8 af = *(const bh8*)(smem + ra * 256 + ((pc ^ (ra & 7)) << 4));
        bh8 bf = *(const bh8*)(smem + 16384 + rb * 256 + ((pc ^ (rb & 7)) << 4));
        sac = mfma16(af, bf, sac);
      }
      if (t2 == 0) sac0 = sac; else sac1 = sac;
    }
    pbar();  // zrow complete; Lk/Lv reads done -> smem reusable
    // ---- scatter S into LDS [2 heads][32x32] f32, then coalesced stores
    float* Sb = (float*)smem;  // 8 KB
#pragma unroll
    for (int t2 = 0; t2 < 2; ++t2) {
      int tk = wid * 2 + t2;
      int hl = tk >> 2, quad = tk & 3;
      int drow = (quad >> 1) * 16, erow = (quad & 1) * 16;
      fx4 sv = (t2 == 0) ? sac0 : sac1;
#pragma unroll
      for (int j = 0; j < 4; ++j)
        Sb[hl * 1024 + (drow + fq * 4 + j) * 32 + erow + fr] = sv[j];
    }
    __syncthreads();
    {
      int hl = tid >> 7, idx = tid & 127;
      float* sp = S_part + ((size_t)((b * 8 + hp * 2 + hl) * 128 + bx)) * 1024;
      fx4 v0 = *(const fx4*)&Sb[hl * 1024 + idx * 8];
      fx4 v1 = *(const fx4*)&Sb[hl * 1024 + idx * 8 + 4];
      *(fx4*)&sp[idx * 8] = v0;
      *(fx4*)&sp[idx * 8 + 4] = v1;
    }
    if (tid < 64) {
      int head = hp * 2 + (tid >> 5);
      Zpart[((size_t)(b * 8 + head) * 128 + bx) * 32 + (tid & 31)] = zrow[tid];
    }
  } else {
    // ---- epilogue B: per m-slice LDS bounce -> full-line coalesced writes
    const size_t obase =
        (size_t)b * CDIM * NPIX + (size_t)(by * 128) * NPIX + (size_t)bx * 128;
    float* Ls = (float*)smem;  // [32][132] f32
#pragma unroll
    for (int m = 0; m < 4; ++m) {
      __syncthreads();
#pragma unroll
      for (int n = 0; n < 4; ++n)
#pragma unroll
        for (int j = 0; j < 4; ++j)
          Ls[(wm * 16 + fq * 4 + j) * 132 + wn * 64 + n * 16 + fr] =
              acc[m][n][j] + bias[by * 128 + wm * 64 + m * 16 + fq * 4 + j];
      __syncthreads();
#pragma unroll
      for (int it = 0; it < 4; ++it) {
        int u = it * 256 + tid;
        int rr = u >> 5, cc = u & 31;
        int gch = (rr >> 4) * 64 + m * 16 + (rr & 15);
        fx4 val = *(const fx4*)&Ls[rr * 132 + cc * 4];
        *(fx4*)&fout[obase + (size_t)gch * NPIX + cc * 4] = val;
      }
    }
  }
}

// -------- pass 2.5: reduce S_part/Zpart over 128 chunks, fused make_w2 ------
__global__ __launch_bounds__(256) void reduce_w2(const float* __restrict__ S_part,
                                                 const float* __restrict__ Zpart,
                                                 const float* __restrict__ w_out,
                                                 __bf16* __restrict__ W2b) {
  const int seg = blockIdx.x;  // 0..3 -> d-range seg*8..+8
  const int bh = blockIdx.y;   // 0..63
  const int b = bh >> 3, h = bh & 7;
  const int t = threadIdx.x;
  __shared__ float zs[8];
  __shared__ float ctxl[256];  // [8 d][32 e]
  if (t < 8) zs[t] = 0.f;
  __syncthreads();
  {
    int row = seg * 8 + (t >> 5);
    float z = 0.f;
    for (int ch = (t & 31); ch < 128; ch += 32)
      z += Zpart[((size_t)bh * 128 + ch) * 32 + row];
    atomicAdd(&zs[t >> 5], z);
  }
  __syncthreads();
  const int i = seg * 256 + t;  // global i = d*32 + e
  float s = 0.f;
  for (int ch = 0; ch < 128; ++ch) s += S_part[((size_t)bh * 128 + ch) * 1024 + i];
  ctxl[t] = s / zs[t >> 5];
  __syncthreads();
  const float* wrow = w_out + t * 256 + h * 32;
  float wv[32];
#pragma unroll
  for (int e = 0; e < 32; ++e) wv[e] = wrow[e];
#pragma unroll
  for (int dp = 0; dp < 8; ++dp) {
    float sacc = 0.f;
#pragma unroll
    for (int e = 0; e < 32; ++e) sacc += wv[e] * ctxl[dp * 32 + e];
    W2b[((size_t)b * 256 + t) * 256 + h * 32 + seg * 8 + dp] = (__bf16)sacc;
  }
}

// -------- pass 3.5: W3[b] = W2b[b] x Wq (via WqT), MFMA ---------------------
__global__ __launch_bounds__(256) void make_w3(const __bf16* __restrict__ W2b,
                                               const __bf16* __restrict__ wqT,
                                               __bf16* __restrict__ W3) {
  const int bx = blockIdx.x, by = blockIdx.y, b = blockIdx.z;
  const int lane = threadIdx.x & 63, wid = threadIdx.x >> 6;
  const int wm = wid >> 1, wn = wid & 1;
  const int fr = lane & 15, fq = lane >> 4;
  const __bf16* Ab = W2b + (size_t)b * 65536 + (size_t)(by * 128 + wm * 64) * 256;
  const __bf16* Bb = wqT + (size_t)(bx * 128 + wn * 64) * 256;
  fx4 acc[4][4] = {};
#pragma unroll
  for (int h = 0; h < 8; ++h) {
    bh8 a_[4], b_[4];
#pragma unroll
    for (int m = 0; m < 4; ++m)
      a_[m] = *(const bh8*)(Ab + (size_t)(m * 16 + fr) * 256 + h * 32 + fq * 8);
#pragma unroll
    for (int n = 0; n < 4; ++n)
      b_[n] = *(const bh8*)(Bb + (size_t)(n * 16 + fr) * 256 + h * 32 + fq * 8);
#pragma unroll
    for (int m = 0; m < 4; ++m)
#pragma unroll
      for (int n = 0; n < 4; ++n) acc[m][n] = mfma16(a_[m], b_[n], acc[m][n]);
  }
#pragma unroll
  for (int m = 0; m < 4; ++m)
#pragma unroll
    for (int n = 0; n < 4; ++n) {
      int r0 = by * 128 + wm * 64 + m * 16 + fq * 4;
      int t0 = bx * 128 + wn * 64 + n * 16 + fr;
#pragma unroll
      for (int j = 0; j < 4; ++j)
        W3[(size_t)b * 65536 + (size_t)(r0 + j) * 256 + t0] = (__bf16)acc[m][n][j];
    }
}

extern "C" void kernel_launch(void* const* d_in, const int* in_sizes, int n_in,
                              void* d_out, int out_size, void* d_ws, size_t ws_size,
                              hipStream_t stream) {
  const float* x     = (const float*)d_in[0];
  const float* w_qkv = (const float*)d_in[1];
  const float* w_out = (const float*)d_in[2];
  const float* b_out = (const float*)d_in[3];
  float* out = (float*)d_out;

  char* ws = (char*)d_ws;
  __bf16* wqb   = (__bf16*)(ws);                     // 262,144 (k,v rows only)
  __bf16* wqT   = (__bf16*)(ws + 262144ull);         // 131,072
  __bf16* W2b   = (__bf16*)(ws + 393216ull);         // 1,048,576
  __bf16* W3    = (__bf16*)(ws + 1441792ull);        // 1,048,576
  float*  S_part= (float*) (ws + 2490368ull);        // 33,554,432 (f32)
  float*  Zpart = (float*) (ws + 36044800ull);       // 1,048,576 (end ~35.4 MB)

  prep_w<<<576, 256, 0, stream>>>(w_qkv, wqb, wqT);
  gemm256<0><<<dim3(4, NPIX / 128, BATCH), 256, 0, stream>>>(
      wqb, x, S_part, Zpart, nullptr, nullptr);
  reduce_w2<<<dim3(4, 64), 256, 0, stream>>>(S_part, Zpart, w_out, W2b);
  make_w3<<<dim3(2, 2, BATCH), 256, 0, stream>>>(W2b, wqT, W3);
  gemm256<1><<<dim3(2, NPIX / 128, BATCH), 256, 0, stream>>>(
      W3, x, nullptr, nullptr, b_out, out);
}

// Round 19
// 167.059 us; speedup vs baseline: 1.1204x; 1.1204x over previous
//
#include <hip/hip_runtime.h>
#include <hip/hip_bf16.h>
#include <cstdint>

#define NPIX 16384   // h*w = 128*128
#define BATCH 8
#define CDIM 256

typedef __bf16 bh8 __attribute__((ext_vector_type(8)));
typedef float  fx4 __attribute__((ext_vector_type(4)));

__device__ __forceinline__ void gload16(const void* g, void* l) {
  __builtin_amdgcn_global_load_lds(
      (const __attribute__((address_space(1))) uint32_t*)g,
      (__attribute__((address_space(3))) uint32_t*)l, 16, 0, 0);
}

__device__ __forceinline__ fx4 mfma16(bh8 a, bh8 b, fx4 c) {
  return __builtin_amdgcn_mfma_f32_16x16x32_bf16(a, b, c, 0, 0, 0);
}

__device__ __forceinline__ void pbar() {
  asm volatile("" ::: "memory");
  __builtin_amdgcn_s_barrier();
  asm volatile("" ::: "memory");
}
#define VMWI(n) asm volatile("s_waitcnt vmcnt(" #n ")" ::: "memory")

// -------- pass 0: x transpose + (slice z==8) weight prep --------------------
// z<8 : x [b][256][NPIX] f32 -> xT [b][NPIX][256] bf16, 64c x 64n tiles.
// z==8: bid<512 -> wqb (k,v rows f32->bf16); bid<576 -> WqT; else idle.
__global__ __launch_bounds__(256) void transpose_x(const float* __restrict__ x,
                                                   __bf16* __restrict__ xT,
                                                   const float* __restrict__ w_qkv,
                                                   __bf16* __restrict__ wqb,
                                                   __bf16* __restrict__ wqT) {
  __shared__ float tf[64][68];
  const int b = blockIdx.z;
  const int u = threadIdx.x;
  if (b == 8) {
    int bid = blockIdx.x * 4 + blockIdx.y;  // 0..1023
    if (bid < 512) {
      int i = bid * 256 + u;
      wqb[i] = (__bf16)w_qkv[256 * 256 + i];
    } else if (bid < 576) {
      bid -= 512;
      float (*tile)[33] = (float(*)[33])tf;
      const int t0 = (bid & 7) * 32, o0 = (bid >> 3) * 32;
      const int tx = u & 31, ty = u >> 5;
#pragma unroll
      for (int j = 0; j < 4; ++j) {
        int r = ty * 4 + j;
        tile[r][tx] = w_qkv[(size_t)(o0 + r) * 256 + t0 + tx];
      }
      __syncthreads();
#pragma unroll
      for (int j = 0; j < 4; ++j) {
        int tl = ty * 4 + j;
        wqT[(size_t)(t0 + tl) * 256 + o0 + tx] = (__bf16)tile[tx][tl];
      }
    }
    return;
  }
  const int n0 = blockIdx.x * 64, c0 = blockIdx.y * 64;
#pragma unroll
  for (int i = 0; i < 4; ++i) {
    int j = i * 256 + u;
    int r = j >> 4, q = j & 15;
    *(fx4*)&tf[r][q * 4] =
        *(const fx4*)&x[((size_t)b * CDIM + c0 + r) * NPIX + n0 + q * 4];
  }
  __syncthreads();
  const int nl = u >> 2, cq = (u & 3) * 16;
#pragma unroll
  for (int w = 0; w < 2; ++w) {
    bh8 v;
#pragma unroll
    for (int j = 0; j < 8; ++j) v[j] = (__bf16)tf[cq + w * 8 + j][nl];
    *(bh8*)&xT[((size_t)b * NPIX + n0 + nl) * CDIM + c0 + cq + w * 8] = v;
  }
}

// ====== 128x128 tile GEMM (m97 proportions), K=256 as 4 x BK=64 =============
// 256 threads / 4 waves (2x2), single-buffered LDS (A 16KB + B 16KB),
// vmcnt(0)-drain schedule (audit-free), chunk-XOR swizzle (0-conflict).
// __launch_bounds__(256,4): 4 blocks/CU (LDS 33KB x4 = 132KB), 16 waves/CU.
// EPI==0: by=head-pair hp (0..3); A rows = 64 k-rows || 64 v-rows of hp.
//         Epilogue: Lk/Lv 64x128 -> per-head S (2 heads x 4 quads) + Z;
//         S partials f32 (bf16 tripped the jax-ref check in r16).
//         r18 lesson: fusing the x-transpose into B-staging 2x-fetched f32 x
//         (263 MB vs 67 MB bf16 xT) -- standalone transpose is cheaper.
// EPI==1: by=row-half (0..1) of W3[b]; writes f32 out + bias via LDS bounce.

#define BSP ((__bf16*)(smem + 16384))

#define STA(kt)                                                                \
  do {                                                                         \
    _Pragma("unroll") for (int i_ = 0; i_ < 4; ++i_) {                         \
      int j_ = i_ * 256 + tid;                                                 \
      int row_ = j_ >> 3, c_ = j_ & 7;                                         \
      int sc_ = c_ ^ (row_ & 7);                                               \
      const __bf16* sb_;                                                       \
      if (EPI == 0) sb_ = (i_ < 2) ? Abk + (size_t)row_ * 256                  \
                                   : Abv + (size_t)(row_ - 64) * 256;          \
      else          sb_ = Ab + (size_t)row_ * 256;                             \
      gload16(sb_ + (kt)*64 + sc_ * 8, (__bf16*)smem + j_ * 8);                \
    }                                                                          \
  } while (0)

#define STB(kt)                                                                \
  do {                                                                         \
    _Pragma("unroll") for (int i_ = 0; i_ < 4; ++i_) {                         \
      int j_ = i_ * 256 + tid;                                                 \
      int row_ = j_ >> 3, c_ = j_ & 7;                                         \
      int sc_ = c_ ^ (row_ & 7);                                               \
      gload16(Bb + (size_t)row_ * 256 + (kt)*64 + sc_ * 8, BSP + j_ * 8);      \
    }                                                                          \
  } while (0)

#define COMP()                                                                 \
  do {                                                                         \
    _Pragma("unroll") for (int ks_ = 0; ks_ < 2; ++ks_) {                      \
      bh8 a_[4], b_[4];                                                        \
      const int swk_ = (ks_ * 4 + fq) ^ (fr & 7);                              \
      _Pragma("unroll") for (int m_ = 0; m_ < 4; ++m_)                         \
        a_[m_] = *(const bh8*)&((__bf16*)smem)[(wm * 64 + m_ * 16 + fr) * 64 + \
                                               swk_ * 8];                      \
      _Pragma("unroll") for (int n_ = 0; n_ < 4; ++n_)                         \
        b_[n_] = *(const bh8*)&BSP[(wn * 64 + n_ * 16 + fr) * 64 + swk_ * 8];  \
      _Pragma("unroll") for (int m_ = 0; m_ < 4; ++m_)                         \
      _Pragma("unroll") for (int n_ = 0; n_ < 4; ++n_)                         \
        acc[m_][n_] = mfma16(a_[m_], b_[n_], acc[m_][n_]);                     \
    }                                                                          \
  } while (0)

template <int EPI>
__global__ __launch_bounds__(256, 4) void gemm256(
    const __bf16* __restrict__ A, const __bf16* __restrict__ Bx,
    float* __restrict__ S_part, float* __restrict__ Zpart,
    const float* __restrict__ bias, float* __restrict__ fout) {
  __shared__ __align__(16) char smem[33024];
  const int tid = threadIdx.x;
  const int by = blockIdx.x;   // EPI0: head-pair hp; EPI1: row-half
  const int bx = blockIdx.y;   // pixel tile (adjacent by share it -> L2)
  const int b = blockIdx.z;
  const int lane = tid & 63, wid = tid >> 6;
  const int wm = wid >> 1, wn = wid & 1;
  const int fr = lane & 15, fq = lane >> 4;
  const int hp = by;  // EPI==0 head-pair (2 heads)
  // wqb holds w_qkv rows 256..767: k at [0,256), v at [256,512)
  const __bf16* Abk = A + (size_t)(hp * 64) * 256;
  const __bf16* Abv = A + (size_t)(256 + hp * 64) * 256;
  const __bf16* Ab  = A + (size_t)b * 65536 + (size_t)by * 128 * 256;
  const __bf16* Bb = Bx + ((size_t)b * NPIX + (size_t)bx * 128) * 256;

  fx4 acc[4][4] = {};

  STA(0); STB(0); VMWI(0); pbar(); COMP(); pbar();
  STA(1); STB(1); VMWI(0); pbar(); COMP(); pbar();
  STA(2); STB(2); VMWI(0); pbar(); COMP(); pbar();
  STA(3); STB(3); VMWI(0); pbar(); COMP(); pbar();

  if (EPI == 0) {
    // ---- epilogue A: Lk (exp(k), 64x128) @0, Lv (v, 64x128) @16384,
    // chunk-XOR swizzled 256B rows; zrow (64 f32) @32768.
    float* zrow = (float*)(smem + 32768);
    if (tid < 64) zrow[tid] = 0.f;
#pragma unroll
    for (int m = 0; m < 4; ++m)
#pragma unroll
      for (int n = 0; n < 4; ++n)
#pragma unroll
        for (int j = 0; j < 4; ++j) {
          int r = m * 16 + fq * 4 + j;             // 0..63 within k or v half
          int px = wn * 64 + n * 16 + fr;          // 0..127
          int pc = px >> 3;
          int byo = r * 256 + ((pc ^ (r & 7)) << 4) + (px & 7) * 2;
          if (wm == 0)
            *(__bf16*)(smem + byo) = (__bf16)__expf(acc[m][n][j]);
          else
            *(__bf16*)(smem + 16384 + byo) = (__bf16)acc[m][n][j];
        }
    pbar();
    {  // Z: 4 threads per k-row, 32 px each
      int r = tid >> 2, c0 = (tid & 3) * 32;
      float za = 0.f;
#pragma unroll
      for (int i2 = 0; i2 < 4; ++i2) {
        int pc = (c0 + i2 * 8) >> 3;
        bh8 ev = *(const bh8*)(smem + r * 256 + ((pc ^ (r & 7)) << 4));
#pragma unroll
        for (int jj = 0; jj < 8; ++jj) za += (float)ev[jj];
      }
      atomicAdd(&zrow[r], za);
    }
    // S: 8 tasks (2 heads x 4 quadrants) over 4 waves, 2 tasks/wave
    fx4 sac0 = {}, sac1 = {};
#pragma unroll
    for (int t2 = 0; t2 < 2; ++t2) {
      int tk = wid * 2 + t2;
      int hl = tk >> 2, quad = tk & 3;
      int drow = (quad >> 1) * 16, erow = (quad & 1) * 16;
      fx4 sac = {};
#pragma unroll
      for (int kt2 = 0; kt2 < 4; ++kt2) {
        int ra = hl * 32 + drow + fr;
        int rb = hl * 32 + erow + fr;
        int pc = kt2 * 4 + fq;
        bh8 af = *(const bh8*)(smem + ra * 256 + ((pc ^ (ra & 7)) << 4));
        bh8 bf = *(const bh8*)(smem + 16384 + rb * 256 + ((pc ^ (rb & 7)) << 4));
        sac = mfma16(af, bf, sac);
      }
      if (t2 == 0) sac0 = sac; else sac1 = sac;
    }
    pbar();  // zrow complete; Lk/Lv reads done -> smem reusable
    // ---- scatter S into LDS [2 heads][32x32] f32, then coalesced stores
    float* Sb = (float*)smem;  // 8 KB
#pragma unroll
    for (int t2 = 0; t2 < 2; ++t2) {
      int tk = wid * 2 + t2;
      int hl = tk >> 2, quad = tk & 3;
      int drow = (quad >> 1) * 16, erow = (quad & 1) * 16;
      fx4 sv = (t2 == 0) ? sac0 : sac1;
#pragma unroll
      for (int j = 0; j < 4; ++j)
        Sb[hl * 1024 + (drow + fq * 4 + j) * 32 + erow + fr] = sv[j];
    }
    __syncthreads();
    {
      int hl = tid >> 7, idx = tid & 127;
      float* sp = S_part + ((size_t)((b * 8 + hp * 2 + hl) * 128 + bx)) * 1024;
      fx4 v0 = *(const fx4*)&Sb[hl * 1024 + idx * 8];
      fx4 v1 = *(const fx4*)&Sb[hl * 1024 + idx * 8 + 4];
      *(fx4*)&sp[idx * 8] = v0;
      *(fx4*)&sp[idx * 8 + 4] = v1;
    }
    if (tid < 64) {
      int head = hp * 2 + (tid >> 5);
      Zpart[((size_t)(b * 8 + head) * 128 + bx) * 32 + (tid & 31)] = zrow[tid];
    }
  } else {
    // ---- epilogue B: per m-slice LDS bounce -> full-line coalesced writes
    const size_t obase =
        (size_t)b * CDIM * NPIX + (size_t)(by * 128) * NPIX + (size_t)bx * 128;
    float* Ls = (float*)smem;  // [32][132] f32
#pragma unroll
    for (int m = 0; m < 4; ++m) {
      __syncthreads();
#pragma unroll
      for (int n = 0; n < 4; ++n)
#pragma unroll
        for (int j = 0; j < 4; ++j)
          Ls[(wm * 16 + fq * 4 + j) * 132 + wn * 64 + n * 16 + fr] =
              acc[m][n][j] + bias[by * 128 + wm * 64 + m * 16 + fq * 4 + j];
      __syncthreads();
#pragma unroll
      for (int it = 0; it < 4; ++it) {
        int u = it * 256 + tid;
        int rr = u >> 5, cc = u & 31;
        int gch = (rr >> 4) * 64 + m * 16 + (rr & 15);
        fx4 val = *(const fx4*)&Ls[rr * 132 + cc * 4];
        *(fx4*)&fout[obase + (size_t)gch * NPIX + cc * 4] = val;
      }
    }
  }
}

// -------- pass 2.5: reduce S_part/Zpart over 128 chunks, fused make_w2 ------
// grid (4 segs, 64 bh). Each block: ctx slice [8 d][32 e] in LDS, then
// W2b[b][oc][h*32+seg*8+d'] = sum_e w_out[oc][h*32+e] * ctx[d'][e].
__global__ __launch_bounds__(256) void reduce_w2(const float* __restrict__ S_part,
                                                 const float* __restrict__ Zpart,
                                                 const float* __restrict__ w_out,
                                                 __bf16* __restrict__ W2b) {
  const int seg = blockIdx.x;  // 0..3 -> d-range seg*8..+8
  const int bh = blockIdx.y;   // 0..63
  const int b = bh >> 3, h = bh & 7;
  const int t = threadIdx.x;
  __shared__ float zs[8];
  __shared__ float ctxl[256];  // [8 d][32 e]
  if (t < 8) zs[t] = 0.f;
  __syncthreads();
  {
    int row = seg * 8 + (t >> 5);
    float z = 0.f;
    for (int ch = (t & 31); ch < 128; ch += 32)
      z += Zpart[((size_t)bh * 128 + ch) * 32 + row];
    atomicAdd(&zs[t >> 5], z);
  }
  __syncthreads();
  const int i = seg * 256 + t;  // global i = d*32 + e
  float s = 0.f;
  for (int ch = 0; ch < 128; ++ch) s += S_part[((size_t)bh * 128 + ch) * 1024 + i];
  ctxl[t] = s / zs[t >> 5];
  __syncthreads();
  const float* wrow = w_out + t * 256 + h * 32;
  float wv[32];
#pragma unroll
  for (int e = 0; e < 32; ++e) wv[e] = wrow[e];
#pragma unroll
  for (int dp = 0; dp < 8; ++dp) {
    float sacc = 0.f;
#pragma unroll
    for (int e = 0; e < 32; ++e) sacc += wv[e] * ctxl[dp * 32 + e];
    W2b[((size_t)b * 256 + t) * 256 + h * 32 + seg * 8 + dp] = (__bf16)sacc;
  }
}

// -------- pass 3.5: W3[b] = W2b[b] x Wq (via WqT), MFMA ---------------------
__global__ __launch_bounds__(256) void make_w3(const __bf16* __restrict__ W2b,
                                               const __bf16* __restrict__ wqT,
                                               __bf16* __restrict__ W3) {
  const int bx = blockIdx.x, by = blockIdx.y, b = blockIdx.z;
  const int lane = threadIdx.x & 63, wid = threadIdx.x >> 6;
  const int wm = wid >> 1, wn = wid & 1;
  const int fr = lane & 15, fq = lane >> 4;
  const __bf16* Ab = W2b + (size_t)b * 65536 + (size_t)(by * 128 + wm * 64) * 256;
  const __bf16* Bb = wqT + (size_t)(bx * 128 + wn * 64) * 256;
  fx4 acc[4][4] = {};
#pragma unroll
  for (int h = 0; h < 8; ++h) {
    bh8 a_[4], b_[4];
#pragma unroll
    for (int m = 0; m < 4; ++m)
      a_[m] = *(const bh8*)(Ab + (size_t)(m * 16 + fr) * 256 + h * 32 + fq * 8);
#pragma unroll
    for (int n = 0; n < 4; ++n)
      b_[n] = *(const bh8*)(Bb + (size_t)(n * 16 + fr) * 256 + h * 32 + fq * 8);
#pragma unroll
    for (int m = 0; m < 4; ++m)
#pragma unroll
      for (int n = 0; n < 4; ++n) acc[m][n] = mfma16(a_[m], b_[n], acc[m][n]);
  }
#pragma unroll
  for (int m = 0; m < 4; ++m)
#pragma unroll
    for (int n = 0; n < 4; ++n) {
      int r0 = by * 128 + wm * 64 + m * 16 + fq * 4;
      int t0 = bx * 128 + wn * 64 + n * 16 + fr;
#pragma unroll
      for (int j = 0; j < 4; ++j)
        W3[(size_t)b * 65536 + (size_t)(r0 + j) * 256 + t0] = (__bf16)acc[m][n][j];
    }
}

extern "C" void kernel_launch(void* const* d_in, const int* in_sizes, int n_in,
                              void* d_out, int out_size, void* d_ws, size_t ws_size,
                              hipStream_t stream) {
  const float* x     = (const float*)d_in[0];
  const float* w_qkv = (const float*)d_in[1];
  const float* w_out = (const float*)d_in[2];
  const float* b_out = (const float*)d_in[3];
  float* out = (float*)d_out;

  char* ws = (char*)d_ws;
  __bf16* xT    = (__bf16*)(ws);                     // 67,108,864
  __bf16* wqb   = (__bf16*)(ws + 67108864ull);       // 262,144 (k,v rows only)
  __bf16* wqT   = (__bf16*)(ws + 67371008ull);       // 131,072
  __bf16* W2b   = (__bf16*)(ws + 67502080ull);       // 1,048,576
  __bf16* W3    = (__bf16*)(ws + 68550656ull);       // 1,048,576
  float*  S_part= (float*) (ws + 69599232ull);       // 33,554,432 (f32)
  float*  Zpart = (float*) (ws + 103153664ull);      // 1,048,576 (end ~99.4 MB)

  transpose_x<<<dim3(NPIX / 64, CDIM / 64, BATCH + 1), 256, 0, stream>>>(
      x, xT, w_qkv, wqb, wqT);
  gemm256<0><<<dim3(4, NPIX / 128, BATCH), 256, 0, stream>>>(
      wqb, xT, S_part, Zpart, nullptr, nullptr);
  reduce_w2<<<dim3(4, 64), 256, 0, stream>>>(S_part, Zpart, w_out, W2b);
  make_w3<<<dim3(2, 2, BATCH), 256, 0, stream>>>(W2b, wqT, W3);
  gemm256<1><<<dim3(2, NPIX / 128, BATCH), 256, 0, stream>>>(
      W3, xT, nullptr, nullptr, b_out, out);
}